// Round 1
// baseline (1998.874 us; speedup 1.0000x reference)
//
#include <hip/hip_runtime.h>
#include <hip/hip_bf16.h>

typedef __attribute__((ext_vector_type(8))) short s16x8;
typedef __attribute__((ext_vector_type(4))) int   i32x4;
typedef __attribute__((ext_vector_type(4))) float f32x4;

#define NCAPS 4608
#define BATCH 128

// ---------------------------------------------------------------------------
// conv2 weights: (9*9*256, 1024) f32 -> transposed bf16 (1024, 20736)
// ---------------------------------------------------------------------------
__global__ void transpose_w_kernel(const float* __restrict__ W,
                                   __hip_bfloat16* __restrict__ Wt) {
  __shared__ float tile[64][65];
  int kt = blockIdx.x * 64;   // k tile (0..20735)
  int ct = blockIdx.y * 64;   // co tile (0..1023)
  for (int i = threadIdx.x; i < 64 * 64; i += 256) {
    int r = i >> 6, c = i & 63;
    tile[r][c] = W[(size_t)(kt + r) * 1024 + ct + c];
  }
  __syncthreads();
  for (int i = threadIdx.x; i < 64 * 64; i += 256) {
    int r = i >> 6, c = i & 63;
    Wt[(size_t)(ct + r) * 20736 + kt + c] = __float2bfloat16(tile[c][r]);
  }
}

// ---------------------------------------------------------------------------
// conv1: (128,32,32,1) x (9,9,1,256) VALID stride1 + bias + relu -> bf16
// one block per (b, oy) row; 256 threads = 256 output channels
// ---------------------------------------------------------------------------
__global__ void conv1_kernel(const float* __restrict__ x,
                             const float* __restrict__ w,
                             const float* __restrict__ bias,
                             __hip_bfloat16* __restrict__ out) {
  int by = blockIdx.x;            // b*24 + y
  int b = by / 24, y = by % 24;
  __shared__ float patch[288];    // 9 rows x 32 cols
  for (int i = threadIdx.x; i < 288; i += 256) {
    int r = i >> 5, c = i & 31;
    patch[i] = x[(size_t)b * 1024 + (y + r) * 32 + c];
  }
  __syncthreads();
  int co = threadIdx.x;
  float bv = bias[co];
  float acc[24];
#pragma unroll
  for (int i = 0; i < 24; i++) acc[i] = bv;
#pragma unroll
  for (int ky = 0; ky < 9; ky++) {
    float row[32];
#pragma unroll
    for (int c = 0; c < 32; c++) row[c] = patch[ky * 32 + c];
#pragma unroll
    for (int kx = 0; kx < 9; kx++) {
      float wv = w[(ky * 9 + kx) * 256 + co];
#pragma unroll
      for (int xx = 0; xx < 24; xx++) acc[xx] += row[kx + xx] * wv;
    }
  }
  size_t obase = (size_t)by * 24 * 256 + co;
#pragma unroll
  for (int xx = 0; xx < 24; xx++)
    out[obase + xx * 256] = __float2bfloat16(fmaxf(acc[xx], 0.f));
}

// ---------------------------------------------------------------------------
// conv2 as implicit GEMM, bf16 MFMA 16x16x32.
// A[m][k]: m=(b,oy,ox) of 18432, k=(ky,kx,ci) of 20736, gathered from conv1out
//          with SAME padding (pad_lo=3), stride 2.
// B^T[n][k]: pre-transposed Wt.
// 128x128 tile, BK=64, 4 waves (2x2), each wave 64x64 (4x4 frags).
// ---------------------------------------------------------------------------
__device__ __forceinline__ int swz(int row, int kb) {
  return row * 128 + (kb ^ ((row & 7) << 4));
}

__global__ void conv2_mfma_kernel(const __hip_bfloat16* __restrict__ A,
                                  const __hip_bfloat16* __restrict__ Wt,
                                  const float* __restrict__ bias,
                                  float* __restrict__ U) {
  __shared__ char As[128 * 128];
  __shared__ char Bs[128 * 128];
  int bn = blockIdx.x;   // 0..7
  int bm = blockIdx.y;   // 0..143
  int tid = threadIdx.x;
  int seg = tid & 7;     // 16B segment in K (8 bf16)
  int r0  = tid >> 3;    // 0..31 (rows r0 + 32*i)

  int iy0[4], ix0[4];
  const __hip_bfloat16* abase[4];
  const __hip_bfloat16* bbase[4];
#pragma unroll
  for (int i = 0; i < 4; i++) {
    int r = r0 + 32 * i;
    int m = bm * 128 + r;
    int b = m / 144, rem = m % 144;
    int oy = rem / 12, ox = rem % 12;
    iy0[i] = oy * 2 - 3;
    ix0[i] = ox * 2 - 3;
    abase[i] = A + (size_t)b * 147456 + seg * 8;
    int n = bn * 128 + r;
    bbase[i] = Wt + (size_t)n * 20736 + seg * 8;
  }

  f32x4 acc[4][4];
#pragma unroll
  for (int mi = 0; mi < 4; mi++)
#pragma unroll
    for (int ni = 0; ni < 4; ni++)
#pragma unroll
      for (int r = 0; r < 4; r++) acc[mi][ni][r] = 0.f;

  int lane = tid & 63, wv = tid >> 6;
  int wm = wv >> 1, wn = wv & 1;
  int lrow = lane & 15;
  int lkb = (lane >> 4) * 16;   // byte offset of this lane's 8 bf16 within K=32 half

  for (int ks = 0; ks < 324; ks++) {
    int k0 = ks * 64;
    int pos = k0 >> 8, ci0 = k0 & 255;
    int ky = pos / 9, kx = pos % 9;
#pragma unroll
    for (int i = 0; i < 4; i++) {
      int iy = iy0[i] + ky, ix = ix0[i] + kx;
      i32x4 val;
      val[0] = 0; val[1] = 0; val[2] = 0; val[3] = 0;
      if (((unsigned)iy < 24u) && ((unsigned)ix < 24u)) {
        int poff = (iy * 24 + ix) * 256 + ci0;
        val = *(const i32x4*)(abase[i] + poff);
      }
      *(i32x4*)(As + swz(r0 + 32 * i, seg * 16)) = val;
      i32x4 wval = *(const i32x4*)(bbase[i] + k0);
      *(i32x4*)(Bs + swz(r0 + 32 * i, seg * 16)) = wval;
    }
    __syncthreads();
#pragma unroll
    for (int ksub = 0; ksub < 2; ksub++) {
      s16x8 af[4], bf[4];
#pragma unroll
      for (int mi = 0; mi < 4; mi++)
        af[mi] = *(const s16x8*)(As + swz(wm * 64 + mi * 16 + lrow, ksub * 64 + lkb));
#pragma unroll
      for (int ni = 0; ni < 4; ni++)
        bf[ni] = *(const s16x8*)(Bs + swz(wn * 64 + ni * 16 + lrow, ksub * 64 + lkb));
#pragma unroll
      for (int mi = 0; mi < 4; mi++)
#pragma unroll
        for (int ni = 0; ni < 4; ni++)
          acc[mi][ni] = __builtin_amdgcn_mfma_f32_16x16x32_bf16(
              af[mi], bf[ni], acc[mi][ni], 0, 0, 0);
    }
    __syncthreads();
  }

  // epilogue: D row = (lane>>4)*4 + reg, col = lane&15  [measured m89/m91]
#pragma unroll
  for (int mi = 0; mi < 4; mi++) {
    int mg = bm * 128 + wm * 64 + mi * 16 + ((lane >> 4) << 2);
#pragma unroll
    for (int ni = 0; ni < 4; ni++) {
      int ng = bn * 128 + wn * 64 + ni * 16 + (lane & 15);
      float bv = bias[ng];
#pragma unroll
      for (int r = 0; r < 4; r++)
        U[(size_t)(mg + r) * 1024 + ng] = acc[mi][ni][r] + bv;
    }
  }
}

// ---------------------------------------------------------------------------
// u_hat[b,n,kd] = sum_p w[n,kd,p] * u[b,n,p]; one block per capsule n.
// ---------------------------------------------------------------------------
__global__ void uhat_kernel(const float* __restrict__ u,
                            const float* __restrict__ w,
                            float* __restrict__ uhat) {
  int n = blockIdx.x;
  __shared__ float wsm[32 * 33];
  int t = threadIdx.x;
  for (int i = t; i < 1024; i += 256)
    wsm[(i >> 5) * 33 + (i & 31)] = w[(size_t)n * 1024 + i];
  __syncthreads();
  int kd = t & 31, bs = t >> 5;
  float wr[32];
#pragma unroll
  for (int p = 0; p < 32; p++) wr[p] = wsm[kd * 33 + p];
  for (int bp = 0; bp < 16; bp++) {
    int b = bp * 8 + bs;
    size_t off = ((size_t)b * NCAPS + n) * 32 + kd;
    float uval = u[off];
    float acc = 0.f;
#pragma unroll
    for (int p = 0; p < 32; p++) acc += wr[p] * __shfl(uval, p, 32);
    uhat[off] = acc;
  }
}

// ---------------------------------------------------------------------------
// routing pass: ITER 0 -> c = 0.5 (softmax of zeros)
//               ITER 1 -> a1 = u_hat.v1 (stored), c = softmax_k(a1)
//               ITER 2 -> c = softmax_k(a1 + u_hat.v2)
// emits per-(b, n-chunk) partial sums of c*u_hat (deterministic 2-stage reduce)
// ---------------------------------------------------------------------------
template <int ITER>
__global__ void routing_kernel(const float* __restrict__ uhat,
                               const float* __restrict__ v,
                               float* __restrict__ a1,
                               float* __restrict__ Spart) {
  int b = blockIdx.y;
  int t = threadIdx.x;
  int n = blockIdx.x * 256 + t;
  __shared__ float vs[32];
  __shared__ float wsum[4][33];
  if (ITER > 0) {
    if (t < 32) vs[t] = v[b * 32 + t];
    __syncthreads();
  }
  float uh[32];
  const float* up = uhat + ((size_t)b * NCAPS + n) * 32;
#pragma unroll
  for (int i = 0; i < 32; i += 4) {
    f32x4 tmp = *(const f32x4*)(up + i);
    uh[i + 0] = tmp[0]; uh[i + 1] = tmp[1];
    uh[i + 2] = tmp[2]; uh[i + 3] = tmp[3];
  }
  float c0 = 0.5f, c1 = 0.5f;
  if (ITER > 0) {
    float d0 = 0.f, d1 = 0.f;
#pragma unroll
    for (int d = 0; d < 16; d++) { d0 += uh[d] * vs[d]; d1 += uh[16 + d] * vs[16 + d]; }
    float b0, b1;
    size_t ai = ((size_t)b * NCAPS + n) * 2;
    if (ITER == 1) {
      a1[ai] = d0; a1[ai + 1] = d1;
      b0 = d0; b1 = d1;
    } else {
      b0 = a1[ai] + d0; b1 = a1[ai + 1] + d1;
    }
    float mx = fmaxf(b0, b1);
    float e0 = __expf(b0 - mx), e1 = __expf(b1 - mx);
    float inv = 1.f / (e0 + e1);
    c0 = e0 * inv; c1 = e1 * inv;
  }
  float val[32];
#pragma unroll
  for (int i = 0; i < 16; i++) { val[i] = c0 * uh[i]; val[16 + i] = c1 * uh[16 + i]; }
#pragma unroll
  for (int m = 1; m < 64; m <<= 1) {
#pragma unroll
    for (int i = 0; i < 32; i++) val[i] += __shfl_xor(val[i], m, 64);
  }
  int lane = t & 63, wid = t >> 6;
  if (lane == 0) {
#pragma unroll
    for (int i = 0; i < 32; i++) wsum[wid][i] = val[i];
  }
  __syncthreads();
  if (t < 32)
    Spart[((size_t)b * 18 + blockIdx.x) * 32 + t] =
        wsum[0][t] + wsum[1][t] + wsum[2][t] + wsum[3][t];
}

// ---------------------------------------------------------------------------
// squash: reduce 18 partials, v = |s|^2/(1+|s|^2) * s/(|s|+eps)
// one block, 256 threads = (b,k) pairs. Final call also writes d_out v + mask.
// ---------------------------------------------------------------------------
__global__ void squash_kernel(const float* __restrict__ Spart,
                              float* __restrict__ v,
                              const float* __restrict__ y,
                              float* __restrict__ vmask,
                              float* __restrict__ vout) {
  int t = threadIdx.x;            // t = b*2 + k
  float s[16];
#pragma unroll
  for (int d = 0; d < 16; d++) s[d] = 0.f;
  const float* p = Spart + (size_t)(t >> 1) * 18 * 32 + (t & 1) * 16;
  for (int ch = 0; ch < 18; ch++) {
#pragma unroll
    for (int d = 0; d < 16; d++) s[d] += p[ch * 32 + d];
  }
  float n2 = 0.f;
#pragma unroll
  for (int d = 0; d < 16; d++) n2 += s[d] * s[d];
  float nrm = sqrtf(n2);
  float f = n2 / (1.f + n2) / (nrm + 1e-7f);
#pragma unroll
  for (int d = 0; d < 16; d++) {
    float vd = s[d] * f;
    v[t * 16 + d] = vd;
    if (vout != nullptr) {
      vout[t * 16 + d] = vd;
      vmask[t * 16 + d] = y[t] * vd;
    }
  }
}

// ---------------------------------------------------------------------------
// decoder dense layer: Y[128,N] = act(X[128,K] @ Wd[K,N] + bias), K,N mult of 32/64
// block: 256 thr = 64 cols x 4 row-groups; each thread 32 rows. grid: N/64.
// ACT: 1 = relu, 2 = sigmoid
// ---------------------------------------------------------------------------
template <int ACT>
__global__ void dense_kernel(const float* __restrict__ X,
                             const float* __restrict__ Wd,
                             const float* __restrict__ bias,
                             float* __restrict__ Y, int K, int N) {
  __shared__ float xs[32][132];   // [kk][b]
  int tx = threadIdx.x & 63, ty = threadIdx.x >> 6;
  int j = blockIdx.x * 64 + tx;
  float acc[32];
#pragma unroll
  for (int i = 0; i < 32; i++) acc[i] = 0.f;
  for (int kc = 0; kc < K; kc += 32) {
    for (int i = threadIdx.x; i < 128 * 32; i += 256) {
      int bb = i >> 5, kk = i & 31;
      xs[kk][bb] = X[(size_t)bb * K + kc + kk];
    }
    __syncthreads();
    for (int kk = 0; kk < 32; kk++) {
      float wvv = Wd[(size_t)(kc + kk) * N + j];
#pragma unroll
      for (int i = 0; i < 32; i++) acc[i] += xs[kk][ty + 4 * i] * wvv;
    }
    __syncthreads();
  }
  float bv = bias[j];
#pragma unroll
  for (int i = 0; i < 32; i++) {
    float r = acc[i] + bv;
    if (ACT == 1) r = fmaxf(r, 0.f);
    else          r = 1.f / (1.f + __expf(-r));
    Y[(size_t)(ty + 4 * i) * N + j] = r;
  }
}

// ---------------------------------------------------------------------------
extern "C" void kernel_launch(void* const* d_in, const int* in_sizes, int n_in,
                              void* d_out, int out_size, void* d_ws, size_t ws_size,
                              hipStream_t stream) {
  const float* input_x = (const float*)d_in[0];
  const float* y       = (const float*)d_in[1];
  const float* conv1_w = (const float*)d_in[2];
  const float* conv1_b = (const float*)d_in[3];
  const float* conv2_w = (const float*)d_in[4];
  const float* conv2_b = (const float*)d_in[5];
  const float* w_caps  = (const float*)d_in[6];
  const float* d1_w    = (const float*)d_in[7];
  const float* d1_b    = (const float*)d_in[8];
  const float* d2_w    = (const float*)d_in[9];
  const float* d2_b    = (const float*)d_in[10];
  const float* d3_w    = (const float*)d_in[11];
  const float* d3_b    = (const float*)d_in[12];
  float* out = (float*)d_out;

  // workspace carve-up (~237 MB)
  char* ws = (char*)d_ws;
  __hip_bfloat16* conv1_out = (__hip_bfloat16*)ws; ws += 37748736;   // 128*24*24*256 bf16
  __hip_bfloat16* Wt        = (__hip_bfloat16*)ws; ws += 42467328;   // 1024*20736 bf16
  float* u     = (float*)ws; ws += 75497472;                          // 128*4608*32 f32
  float* uhat  = (float*)ws; ws += 75497472;                          // 128*4608*32 f32
  float* a1    = (float*)ws; ws += 4718592;                           // 128*4608*2 f32
  float* Spart = (float*)ws; ws += 294912;                            // 128*18*32 f32
  float* vbuf  = (float*)ws; ws += 16384;                             // 128*32 f32
  float* vmask = (float*)ws; ws += 16384;                             // 128*32 f32
  float* h1    = (float*)ws; ws += 131072;                            // 128*256 f32
  float* h2    = (float*)ws; ws += 262144;                            // 128*512 f32

  transpose_w_kernel<<<dim3(324, 16), 256, 0, stream>>>(conv2_w, Wt);
  conv1_kernel<<<3072, 256, 0, stream>>>(input_x, conv1_w, conv1_b, conv1_out);
  conv2_mfma_kernel<<<dim3(8, 144), 256, 0, stream>>>(conv1_out, Wt, conv2_b, u);
  uhat_kernel<<<NCAPS, 256, 0, stream>>>(u, w_caps, uhat);

  routing_kernel<0><<<dim3(18, 128), 256, 0, stream>>>(uhat, nullptr, nullptr, Spart);
  squash_kernel<<<1, 256, 0, stream>>>(Spart, vbuf, nullptr, nullptr, nullptr);
  routing_kernel<1><<<dim3(18, 128), 256, 0, stream>>>(uhat, vbuf, a1, Spart);
  squash_kernel<<<1, 256, 0, stream>>>(Spart, vbuf, nullptr, nullptr, nullptr);
  routing_kernel<2><<<dim3(18, 128), 256, 0, stream>>>(uhat, vbuf, a1, Spart);
  // final squash: writes v into d_out[0:4096] and masked v for the decoder
  squash_kernel<<<1, 256, 0, stream>>>(Spart, vbuf, y, vmask, out);

  dense_kernel<1><<<4, 256, 0, stream>>>(vmask, d1_w, d1_b, h1, 32, 256);
  dense_kernel<1><<<8, 256, 0, stream>>>(h1, d2_w, d2_b, h2, 256, 512);
  dense_kernel<2><<<16, 256, 0, stream>>>(h2, d3_w, d3_b, out + 4096, 512, 1024);
}